// Round 5
// baseline (659.685 us; speedup 1.0000x reference)
//
#include <hip/hip_runtime.h>
#include <hip/hip_bf16.h>

#define N_NODES 4096
#define DIM 256
#define NHEAD 4
#define NEDGE 131072
#define MWORDS 128           // 4096 bits / 32 per mask row
#define MAXDEG 192           // mean deg ~65 (Poisson), 192 is >15 sigma
#define NODE_STRIDE 3072     // [q(1024) | k(1024) | v(1024)] per node

#define BM 128
#define BN 128
#define BK 16

// ---------------------------------------------------------------- mask build
__global__ __launch_bounds__(256) void build_mask_kernel(const int* __restrict__ ei,
                                                         unsigned* __restrict__ mask) {
    const int t = blockIdx.x * blockDim.x + threadIdx.x;
    if (t < NEDGE) {
        const int r = ei[t] & (N_NODES - 1);
        const int c = ei[NEDGE + t] & (N_NODES - 1);
        atomicOr(&mask[r * MWORDS + (c >> 5)], 1u << (c & 31));
        atomicOr(&mask[c * MWORDS + (r >> 5)], 1u << (r & 31));
    } else if (t < NEDGE + N_NODES) {
        const int i = t - NEDGE;
        atomicOr(&mask[i * MWORDS + (i >> 5)], 1u << (i & 31));
    }
}

// ---------------------------------------------------------------- fp32 NT GEMM 128x128
// C = A @ Bblk^T + biasblk ; A [*,K] lda, Bblk rows = this block's 128 out cols (ldb=K)
// Cblk pre-offset to this block's column origin; writes rows bm..bm+127, cols 0..127.
__device__ __forceinline__ void gemm128(const float* __restrict__ A, int lda,
                                        const float* __restrict__ Bblk, int ldb,
                                        const float* __restrict__ biasblk,
                                        float* __restrict__ Cblk, int ldc,
                                        int bm, int K) {
    __shared__ __align__(16) float As[BK][BM + 4];
    __shared__ __align__(16) float Bs[BK][BN + 4];
    const int tid = threadIdx.x;
    const int r = tid & 127;
    const int kc = (tid >> 7) << 3;        // 0 or 8
    const int tx = tid & 15;               // micro col group
    const int ty = tid >> 4;               // micro row group

    const float* Ap = A + (size_t)(bm + r) * lda + kc;
    const float* Bp = Bblk + (size_t)r * ldb + kc;

    float acc[8][8];
#pragma unroll
    for (int i = 0; i < 8; ++i)
#pragma unroll
        for (int j = 0; j < 8; ++j) acc[i][j] = 0.f;

    float4 a0 = *(const float4*)(Ap);
    float4 a1 = *(const float4*)(Ap + 4);
    float4 b0 = *(const float4*)(Bp);
    float4 b1 = *(const float4*)(Bp + 4);

    for (int k0 = 0; k0 < K; k0 += BK) {
        __syncthreads();
        As[kc + 0][r] = a0.x; As[kc + 1][r] = a0.y; As[kc + 2][r] = a0.z; As[kc + 3][r] = a0.w;
        As[kc + 4][r] = a1.x; As[kc + 5][r] = a1.y; As[kc + 6][r] = a1.z; As[kc + 7][r] = a1.w;
        Bs[kc + 0][r] = b0.x; Bs[kc + 1][r] = b0.y; Bs[kc + 2][r] = b0.z; Bs[kc + 3][r] = b0.w;
        Bs[kc + 4][r] = b1.x; Bs[kc + 5][r] = b1.y; Bs[kc + 6][r] = b1.z; Bs[kc + 7][r] = b1.w;
        __syncthreads();
        if (k0 + BK < K) {
            a0 = *(const float4*)(Ap + k0 + BK);
            a1 = *(const float4*)(Ap + k0 + BK + 4);
            b0 = *(const float4*)(Bp + k0 + BK);
            b1 = *(const float4*)(Bp + k0 + BK + 4);
        }
#pragma unroll
        for (int k = 0; k < BK; ++k) {
            float af[8], bf[8];
            *(float4*)&af[0] = *(const float4*)&As[k][ty << 3];
            *(float4*)&af[4] = *(const float4*)&As[k][(ty << 3) + 4];
            *(float4*)&bf[0] = *(const float4*)&Bs[k][tx << 3];
            *(float4*)&bf[4] = *(const float4*)&Bs[k][(tx << 3) + 4];
#pragma unroll
            for (int i = 0; i < 8; ++i)
#pragma unroll
                for (int j = 0; j < 8; ++j) acc[i][j] += af[i] * bf[j];
        }
    }
    const int c0 = tx << 3;
    const float4 bia0 = *(const float4*)&biasblk[c0];
    const float4 bia1 = *(const float4*)&biasblk[c0 + 4];
#pragma unroll
    for (int i = 0; i < 8; ++i) {
        const int row = bm + (ty << 3) + i;
        float4 r0, r1;
        r0.x = acc[i][0] + bia0.x; r0.y = acc[i][1] + bia0.y;
        r0.z = acc[i][2] + bia0.z; r0.w = acc[i][3] + bia0.w;
        r1.x = acc[i][4] + bia1.x; r1.y = acc[i][5] + bia1.y;
        r1.z = acc[i][6] + bia1.z; r1.w = acc[i][7] + bia1.w;
        *(float4*)&Cblk[(size_t)row * ldc + c0] = r0;
        *(float4*)&Cblk[(size_t)row * ldc + c0 + 4] = r1;
    }
}

// fused QKV: out cols 0..3071 = [q h0..h3 | k h0..h3 | v h0..h3], node-major rows
__global__ __launch_bounds__(256) void qkv_kernel(const float* __restrict__ x,
                                                  const float* __restrict__ Wq, const float* __restrict__ bq,
                                                  const float* __restrict__ Wk, const float* __restrict__ bk,
                                                  const float* __restrict__ Wv, const float* __restrict__ bv,
                                                  float* __restrict__ qkv) {
    const int by = blockIdx.y;           // 0..23
    const int op = by >> 3;              // 0:q 1:k 2:v
    const int byo = by & 7;
    const int h = byo >> 1;
    const int cb = (byo & 1) * 128;      // col offset within head
    const float* W = (op == 0 ? Wq : op == 1 ? Wk : Wv) + h * DIM * DIM + cb * DIM;
    const float* bb = (op == 0 ? bq : op == 1 ? bk : bv) + h * DIM + cb;
    float* Cb = qkv + op * 1024 + h * DIM + cb;
    gemm128(x, DIM, W, DIM, bb, Cb, NODE_STRIDE, blockIdx.x * BM, DIM);
}

// per-head out-proj (block-diagonal), node-major [N][H*D] in and out
__global__ __launch_bounds__(256) void headout_kernel(const float* __restrict__ o,
                                                      const float* __restrict__ Wo,
                                                      const float* __restrict__ bo,
                                                      float* __restrict__ concat) {
    const int h = blockIdx.z;
    const int cb = blockIdx.y * 128;
    gemm128(o + h * DIM, NHEAD * DIM, Wo + h * DIM * DIM + cb * DIM, DIM,
            bo + h * DIM + cb, concat + h * DIM + cb, NHEAD * DIM,
            blockIdx.x * BM, DIM);
}

// out = concat [N,1024] @ Wp^T + bp -> [N,256]
__global__ __launch_bounds__(256) void finalproj_kernel(const float* __restrict__ concat,
                                                        const float* __restrict__ Wp,
                                                        const float* __restrict__ bp,
                                                        float* __restrict__ outp) {
    const int cb = blockIdx.y * 128;
    gemm128(concat, NHEAD * DIM, Wp + (size_t)cb * (NHEAD * DIM), NHEAD * DIM,
            bp + cb, outp + cb, DIM,
            blockIdx.x * BM, NHEAD * DIM);
}

// ---------------------------------------------------------------- sparse attention
// one block per node; wave = head. Shared mask decode; 16-lane subgroups process
// 4 neighbors concurrently; K and V loads fused per neighbor (4KB apart in the
// node record); V accumulated in-register; cross-subgroup reduce at the end.
__global__ __launch_bounds__(256) void attn_sparse_kernel(const unsigned* __restrict__ mask,
                                                          const float* __restrict__ qkv,
                                                          float* __restrict__ o) {
    __shared__ int nbr[MAXDEG];
    __shared__ int cnt;
    const int i = blockIdx.x;
    const int tid = threadIdx.x;
    if (tid == 0) cnt = 0;
    __syncthreads();
    if (tid < MWORDS) {
        unsigned m = mask[i * MWORDS + tid];
        while (m) {
            const int b = __ffs(m) - 1;
            m &= m - 1;
            const int pos = atomicAdd(&cnt, 1);
            nbr[pos] = (tid << 5) + b;
        }
    }
    __syncthreads();
    const int deg = cnt;

    const int lane = tid & 63;
    const int h = tid >> 6;
    const int sub = lane >> 4;       // which of 4 concurrent neighbors
    const int sl = lane & 15;        // lane's 16-dim slice: dims sl*16..sl*16+15

    const float* qp = qkv + (size_t)i * NODE_STRIDE + h * DIM + (sl << 4);
    const float4 qf0 = *(const float4*)(qp + 0);
    const float4 qf1 = *(const float4*)(qp + 4);
    const float4 qf2 = *(const float4*)(qp + 8);
    const float4 qf3 = *(const float4*)(qp + 12);

    const float SC = 0.0625f * 1.44269504f;   // 1/sqrt(256) * log2(e)
    float denom = 0.f;
    float4 oa0 = {0.f, 0.f, 0.f, 0.f}, oa1 = {0.f, 0.f, 0.f, 0.f};
    float4 oa2 = {0.f, 0.f, 0.f, 0.f}, oa3 = {0.f, 0.f, 0.f, 0.f};

    for (int n0 = 0; n0 < deg; n0 += 4) {
        const int idx = n0 + sub;
        const bool valid = idx < deg;
        const int j = nbr[valid ? idx : 0];
        const float* kp = qkv + (size_t)j * NODE_STRIDE + 1024 + h * DIM + (sl << 4);
        const float4 k0 = *(const float4*)(kp + 0);
        const float4 k1 = *(const float4*)(kp + 4);
        const float4 k2 = *(const float4*)(kp + 8);
        const float4 k3 = *(const float4*)(kp + 12);
        const float4 v0 = *(const float4*)(kp + 1024);
        const float4 v1 = *(const float4*)(kp + 1028);
        const float4 v2 = *(const float4*)(kp + 1032);
        const float4 v3 = *(const float4*)(kp + 1036);
        float p = qf0.x * k0.x + qf0.y * k0.y + qf0.z * k0.z + qf0.w * k0.w;
        p += qf1.x * k1.x + qf1.y * k1.y + qf1.z * k1.z + qf1.w * k1.w;
        p += qf2.x * k2.x + qf2.y * k2.y + qf2.z * k2.z + qf2.w * k2.w;
        p += qf3.x * k3.x + qf3.y * k3.y + qf3.z * k3.z + qf3.w * k3.w;
        p += __shfl_xor(p, 1);
        p += __shfl_xor(p, 2);
        p += __shfl_xor(p, 4);
        p += __shfl_xor(p, 8);
        const float wt = valid ? __builtin_amdgcn_exp2f(p * SC) : 0.f;
        denom += wt;
        oa0.x += wt * v0.x; oa0.y += wt * v0.y; oa0.z += wt * v0.z; oa0.w += wt * v0.w;
        oa1.x += wt * v1.x; oa1.y += wt * v1.y; oa1.z += wt * v1.z; oa1.w += wt * v1.w;
        oa2.x += wt * v2.x; oa2.y += wt * v2.y; oa2.z += wt * v2.z; oa2.w += wt * v2.w;
        oa3.x += wt * v3.x; oa3.y += wt * v3.y; oa3.z += wt * v3.z; oa3.w += wt * v3.w;
    }
    denom += __shfl_xor(denom, 16);
    denom += __shfl_xor(denom, 32);
    const float inv = 1.0f / denom;

    // reduce oa across the 4 subgroups (dims are per-sl, identical across subs)
#define RED(c) c += __shfl_xor(c, 16); c += __shfl_xor(c, 32);
    RED(oa0.x) RED(oa0.y) RED(oa0.z) RED(oa0.w)
    RED(oa1.x) RED(oa1.y) RED(oa1.z) RED(oa1.w)
    RED(oa2.x) RED(oa2.y) RED(oa2.z) RED(oa2.w)
    RED(oa3.x) RED(oa3.y) RED(oa3.z) RED(oa3.w)
#undef RED

    if (sub == 0) {
        float* op_ = o + (size_t)i * (NHEAD * DIM) + h * DIM + (sl << 4);
        float4 r0, r1, r2, r3;
        r0.x = oa0.x * inv; r0.y = oa0.y * inv; r0.z = oa0.z * inv; r0.w = oa0.w * inv;
        r1.x = oa1.x * inv; r1.y = oa1.y * inv; r1.z = oa1.z * inv; r1.w = oa1.w * inv;
        r2.x = oa2.x * inv; r2.y = oa2.y * inv; r2.z = oa2.z * inv; r2.w = oa2.w * inv;
        r3.x = oa3.x * inv; r3.y = oa3.y * inv; r3.z = oa3.z * inv; r3.w = oa3.w * inv;
        *(float4*)(op_ + 0) = r0;
        *(float4*)(op_ + 4) = r1;
        *(float4*)(op_ + 8) = r2;
        *(float4*)(op_ + 12) = r3;
    }
}

// ---------------------------------------------------------------- layernorm
__global__ __launch_bounds__(256) void layernorm_kernel(const float* __restrict__ inp,
                                                        const float* __restrict__ gamma,
                                                        const float* __restrict__ beta,
                                                        float* __restrict__ out) {
    const int row = (blockIdx.x << 2) + (threadIdx.x >> 6);
    const int lane = threadIdx.x & 63;
    const float4 xv = *(const float4*)&inp[row * DIM + (lane << 2)];
    float s = xv.x + xv.y + xv.z + xv.w;
#pragma unroll
    for (int off = 32; off; off >>= 1) s += __shfl_xor(s, off);
    const float mu = s * (1.0f / DIM);
    const float dx = xv.x - mu, dy = xv.y - mu, dz = xv.z - mu, dw = xv.w - mu;
    float sq = dx * dx + dy * dy + dz * dz + dw * dw;
#pragma unroll
    for (int off = 32; off; off >>= 1) sq += __shfl_xor(sq, off);
    const float inv = 1.0f / sqrtf(sq * (1.0f / DIM) + 1e-5f);
    const float4 gv = *(const float4*)&gamma[lane << 2];
    const float4 bv = *(const float4*)&beta[lane << 2];
    float4 r;
    r.x = dx * inv * gv.x + bv.x;
    r.y = dy * inv * gv.y + bv.y;
    r.z = dz * inv * gv.z + bv.z;
    r.w = dw * inv * gv.w + bv.w;
    *(float4*)&out[row * DIM + (lane << 2)] = r;
}

// ---------------------------------------------------------------- launcher
extern "C" void kernel_launch(void* const* d_in, const int* in_sizes, int n_in,
                              void* d_out, int out_size, void* d_ws, size_t ws_size,
                              hipStream_t stream) {
    const float* x     = (const float*)d_in[0];
    const int*   ei    = (const int*)d_in[1];
    const float* Wq    = (const float*)d_in[2];
    const float* bq    = (const float*)d_in[3];
    const float* Wk    = (const float*)d_in[4];
    const float* bk    = (const float*)d_in[5];
    const float* Wv    = (const float*)d_in[6];
    const float* bv    = (const float*)d_in[7];
    const float* Wo    = (const float*)d_in[8];
    const float* bo    = (const float*)d_in[9];
    const float* Wp    = (const float*)d_in[10];
    const float* bp    = (const float*)d_in[11];
    const float* gamma = (const float*)d_in[12];
    const float* beta  = (const float*)d_in[13];
    float* outf = (float*)d_out;

    char* ws = (char*)d_ws;
    unsigned* mask = (unsigned*)ws;                               // 2 MB
    float* qkv  = (float*)(ws + (size_t)(2 << 20));               // 48 MB [N][3072]
    float* obuf = (float*)(ws + (size_t)(50 << 20));              // 16 MB [N][1024]
    float* concat = qkv;                                          // alias: qkv dead after attn
    float* outp = qkv + (size_t)4 * 1024 * 1024;                  // alias: +16MB into qkv region

    hipMemsetAsync(mask, 0, N_NODES * MWORDS * sizeof(unsigned), stream);
    build_mask_kernel<<<(NEDGE + N_NODES + 255) / 256, 256, 0, stream>>>(ei, mask);

    qkv_kernel<<<dim3(N_NODES / BM, 24), 256, 0, stream>>>(x, Wq, bq, Wk, bk, Wv, bv, qkv);

    attn_sparse_kernel<<<N_NODES, 256, 0, stream>>>(mask, qkv, obuf);

    headout_kernel<<<dim3(N_NODES / BM, 2, NHEAD), 256, 0, stream>>>(obuf, Wo, bo, concat);

    finalproj_kernel<<<dim3(N_NODES / BM, 2), 256, 0, stream>>>(concat, Wp, bp, outp);

    layernorm_kernel<<<N_NODES / 4, 256, 0, stream>>>(outp, gamma, beta, outf);
}

// Round 6
// 384.402 us; speedup vs baseline: 1.7161x; 1.7161x over previous
//
#include <hip/hip_runtime.h>
#include <hip/hip_bf16.h>

#define N_NODES 4096
#define DIM 256
#define NHEAD 4
#define NEDGE 131072
#define MWORDS 128           // 4096 bits / 32 per mask row
#define MAXDEG 192           // mean deg ~65 (Poisson); 192 is >15 sigma
#define KV_STRIDE 2048       // bf16 elems per node: 4 heads x (256 k + 256 v)

#define BM 64
#define BN 64
#define BK 16

typedef unsigned short ushort_t;

__device__ __forceinline__ ushort_t f2bf(float f) {
    unsigned u = __float_as_uint(f);
    unsigned r = u + 0x7FFFu + ((u >> 16) & 1u);   // round-to-nearest-even
    return (ushort_t)(r >> 16);
}
__device__ __forceinline__ float bf2f(ushort_t u) {
    return __uint_as_float((unsigned)u << 16);
}

// ---------------------------------------------------------------- mask build
__global__ __launch_bounds__(256) void build_mask_kernel(const int* __restrict__ ei,
                                                         unsigned* __restrict__ mask) {
    const int t = blockIdx.x * blockDim.x + threadIdx.x;
    if (t < NEDGE) {
        const int r = ei[t] & (N_NODES - 1);
        const int c = ei[NEDGE + t] & (N_NODES - 1);
        atomicOr(&mask[r * MWORDS + (c >> 5)], 1u << (c & 31));
        atomicOr(&mask[c * MWORDS + (r >> 5)], 1u << (r & 31));
    } else if (t < NEDGE + N_NODES) {
        const int i = t - NEDGE;
        atomicOr(&mask[i * MWORDS + (i >> 5)], 1u << (i & 31));
    }
}

// ---------------------------------------------------------------- fp32 NT GEMM tile
// C[m][n] = sum_k A[m*lda+k] * B[n*ldb+k] + bias[n]
// MODE 0: C fp32, element stride ldc. MODE 1: C bf16 (ushort), element stride ldc.
template <int MODE>
__device__ __forceinline__ void gemm_nt_64x64(const float* __restrict__ A, int lda,
                                              const float* __restrict__ B, int ldb,
                                              const float* __restrict__ bias,
                                              void* __restrict__ Cv, int ldc,
                                              int bm, int bn, int K) {
    __shared__ float As[BK][BM + 4];
    __shared__ float Bs[BK][BN + 4];
    const int tid = threadIdx.x;
    const int tx = tid & 15;
    const int ty = tid >> 4;
    const int lr = tid >> 2;         // 0..63 : row within tile for loads
    const int lc = (tid & 3) << 2;   // 0,4,8,12 : k-col within chunk
    float acc[4][4] = {{0.f, 0.f, 0.f, 0.f}, {0.f, 0.f, 0.f, 0.f},
                       {0.f, 0.f, 0.f, 0.f}, {0.f, 0.f, 0.f, 0.f}};
    const float* Aload = A + (size_t)(bm + lr) * lda + lc;
    const float* Bload = B + (size_t)(bn + lr) * ldb + lc;
    for (int k0 = 0; k0 < K; k0 += BK) {
        const float4 a4 = *(const float4*)(Aload + k0);
        const float4 b4 = *(const float4*)(Bload + k0);
        __syncthreads();
        As[lc + 0][lr] = a4.x; As[lc + 1][lr] = a4.y;
        As[lc + 2][lr] = a4.z; As[lc + 3][lr] = a4.w;
        Bs[lc + 0][lr] = b4.x; Bs[lc + 1][lr] = b4.y;
        Bs[lc + 2][lr] = b4.z; Bs[lc + 3][lr] = b4.w;
        __syncthreads();
#pragma unroll
        for (int k = 0; k < BK; ++k) {
            const float4 av = *(const float4*)&As[k][ty << 2];
            const float4 bv = *(const float4*)&Bs[k][tx << 2];
            acc[0][0] += av.x * bv.x; acc[0][1] += av.x * bv.y;
            acc[0][2] += av.x * bv.z; acc[0][3] += av.x * bv.w;
            acc[1][0] += av.y * bv.x; acc[1][1] += av.y * bv.y;
            acc[1][2] += av.y * bv.z; acc[1][3] += av.y * bv.w;
            acc[2][0] += av.z * bv.x; acc[2][1] += av.z * bv.y;
            acc[2][2] += av.z * bv.z; acc[2][3] += av.z * bv.w;
            acc[3][0] += av.w * bv.x; acc[3][1] += av.w * bv.y;
            acc[3][2] += av.w * bv.z; acc[3][3] += av.w * bv.w;
        }
    }
    const int col = bn + (tx << 2);
    const float4 bia = *(const float4*)&bias[col];
#pragma unroll
    for (int i = 0; i < 4; ++i) {
        const int row = bm + (ty << 2) + i;
        float r0 = acc[i][0] + bia.x;
        float r1 = acc[i][1] + bia.y;
        float r2 = acc[i][2] + bia.z;
        float r3 = acc[i][3] + bia.w;
        if (MODE == 0) {
            float4 r; r.x = r0; r.y = r1; r.z = r2; r.w = r3;
            *(float4*)&((float*)Cv)[(size_t)row * ldc + col] = r;
        } else {
            ushort4 r;
            r.x = f2bf(r0); r.y = f2bf(r1); r.z = f2bf(r2); r.w = f2bf(r3);
            *(ushort4*)&((ushort_t*)Cv)[(size_t)row * ldc + col] = r;
        }
    }
}

// q/k/v projections: z = op*4 + head.
// q -> fp32 h-major [h][n][256]; k,v -> bf16 records kv[node][h*512 + (k:0|v:256) + col]
__global__ __launch_bounds__(256) void qkv_kernel(const float* __restrict__ x,
                                                  const float* __restrict__ Wq, const float* __restrict__ bq,
                                                  const float* __restrict__ Wk, const float* __restrict__ bk,
                                                  const float* __restrict__ Wv, const float* __restrict__ bv,
                                                  float* __restrict__ q, ushort_t* __restrict__ kv) {
    const int z = blockIdx.z;
    const int op = z >> 2;
    const int h = z & 3;
    const int bm = blockIdx.x * BM;
    const int bn = blockIdx.y * BN;
    if (op == 0) {
        gemm_nt_64x64<0>(x, DIM, Wq + h * DIM * DIM, DIM, bq + h * DIM,
                         q + (size_t)h * N_NODES * DIM, DIM, bm, bn, DIM);
    } else if (op == 1) {
        gemm_nt_64x64<1>(x, DIM, Wk + h * DIM * DIM, DIM, bk + h * DIM,
                         kv + h * 512, KV_STRIDE, bm, bn, DIM);
    } else {
        gemm_nt_64x64<1>(x, DIM, Wv + h * DIM * DIM, DIM, bv + h * DIM,
                         kv + h * 512 + 256, KV_STRIDE, bm, bn, DIM);
    }
}

// per-head out-proj, o fp32 h-major -> concat [N, H*D]
__global__ __launch_bounds__(256) void headout_kernel(const float* __restrict__ o,
                                                      const float* __restrict__ Wo,
                                                      const float* __restrict__ bo,
                                                      float* __restrict__ concat) {
    const int h = blockIdx.z;
    gemm_nt_64x64<0>(o + (size_t)h * N_NODES * DIM, DIM, Wo + h * DIM * DIM, DIM, bo + h * DIM,
                     concat + h * DIM, NHEAD * DIM,
                     blockIdx.x * BM, blockIdx.y * BN, DIM);
}

// out = concat [N,1024] @ Wp^T + bp -> [N,256]
__global__ __launch_bounds__(256) void finalproj_kernel(const float* __restrict__ concat,
                                                        const float* __restrict__ Wp,
                                                        const float* __restrict__ bp,
                                                        float* __restrict__ outp) {
    gemm_nt_64x64<0>(concat, NHEAD * DIM, Wp, NHEAD * DIM, bp,
                     outp, DIM,
                     blockIdx.x * BM, blockIdx.y * BN, NHEAD * DIM);
}

// ---------------------------------------------------------------- sparse attention
// one block per node; wave = head. Shared nbr-list decode; serial one-neighbor-per-
// wave loop (best L2 hit rate observed); bf16 k/v fused in one 1KB record per
// (node,head); fp32 math; full-wave 6-shfl dot reduce.
__global__ __launch_bounds__(256) void attn_sparse_kernel(const unsigned* __restrict__ mask,
                                                          const float* __restrict__ q,
                                                          const ushort_t* __restrict__ kv,
                                                          float* __restrict__ o) {
    __shared__ int nbr[MAXDEG];
    __shared__ int cnt;
    const int i = blockIdx.x;
    const int tid = threadIdx.x;
    if (tid == 0) cnt = 0;
    __syncthreads();
    if (tid < MWORDS) {
        unsigned m = mask[i * MWORDS + tid];
        while (m) {
            const int b = __ffs(m) - 1;
            m &= m - 1;
            const int pos = atomicAdd(&cnt, 1);
            nbr[pos] = (tid << 5) + b;
        }
    }
    __syncthreads();
    const int deg = cnt;

    const int lane = tid & 63;
    const int h = tid >> 6;

    const float4 qf = *(const float4*)&q[(((size_t)h * N_NODES + i) << 8) + (lane << 2)];
    const ushort_t* base = kv + h * 512 + (lane << 2);

    const float SC = 0.0625f * 1.44269504f;   // 1/sqrt(256) * log2(e)
    float denom = 0.f;
    float4 oa = {0.f, 0.f, 0.f, 0.f};

    for (int n = 0; n < deg; ++n) {
        const int j = nbr[n];
        const ushort_t* kp = base + (size_t)j * KV_STRIDE;
        const ushort4 ku = *(const ushort4*)kp;
        const ushort4 vu = *(const ushort4*)(kp + 256);
        float p = qf.x * bf2f(ku.x) + qf.y * bf2f(ku.y)
                + qf.z * bf2f(ku.z) + qf.w * bf2f(ku.w);
        p += __shfl_xor(p, 1);
        p += __shfl_xor(p, 2);
        p += __shfl_xor(p, 4);
        p += __shfl_xor(p, 8);
        p += __shfl_xor(p, 16);
        p += __shfl_xor(p, 32);
        const float wt = __builtin_amdgcn_exp2f(p * SC);
        denom += wt;
        oa.x += wt * bf2f(vu.x);
        oa.y += wt * bf2f(vu.y);
        oa.z += wt * bf2f(vu.z);
        oa.w += wt * bf2f(vu.w);
    }
    const float inv = 1.0f / denom;
    float4 r;
    r.x = oa.x * inv; r.y = oa.y * inv; r.z = oa.z * inv; r.w = oa.w * inv;
    *(float4*)&o[(((size_t)h * N_NODES + i) << 8) + (lane << 2)] = r;
}

// ---------------------------------------------------------------- layernorm
__global__ __launch_bounds__(256) void layernorm_kernel(const float* __restrict__ inp,
                                                        const float* __restrict__ gamma,
                                                        const float* __restrict__ beta,
                                                        float* __restrict__ out) {
    const int row = (blockIdx.x << 2) + (threadIdx.x >> 6);
    const int lane = threadIdx.x & 63;
    const float4 xv = *(const float4*)&inp[row * DIM + (lane << 2)];
    float s = xv.x + xv.y + xv.z + xv.w;
#pragma unroll
    for (int off = 32; off; off >>= 1) s += __shfl_xor(s, off);
    const float mu = s * (1.0f / DIM);
    const float dx = xv.x - mu, dy = xv.y - mu, dz = xv.z - mu, dw = xv.w - mu;
    float sq = dx * dx + dy * dy + dz * dz + dw * dw;
#pragma unroll
    for (int off = 32; off; off >>= 1) sq += __shfl_xor(sq, off);
    const float inv = 1.0f / sqrtf(sq * (1.0f / DIM) + 1e-5f);
    const float4 gv = *(const float4*)&gamma[lane << 2];
    const float4 bv = *(const float4*)&beta[lane << 2];
    float4 r;
    r.x = dx * inv * gv.x + bv.x;
    r.y = dy * inv * gv.y + bv.y;
    r.z = dz * inv * gv.z + bv.z;
    r.w = dw * inv * gv.w + bv.w;
    *(float4*)&out[row * DIM + (lane << 2)] = r;
}

// ---------------------------------------------------------------- launcher
extern "C" void kernel_launch(void* const* d_in, const int* in_sizes, int n_in,
                              void* d_out, int out_size, void* d_ws, size_t ws_size,
                              hipStream_t stream) {
    const float* x     = (const float*)d_in[0];
    const int*   ei    = (const int*)d_in[1];
    const float* Wq    = (const float*)d_in[2];
    const float* bq    = (const float*)d_in[3];
    const float* Wk    = (const float*)d_in[4];
    const float* bk    = (const float*)d_in[5];
    const float* Wv    = (const float*)d_in[6];
    const float* bv    = (const float*)d_in[7];
    const float* Wo    = (const float*)d_in[8];
    const float* bo    = (const float*)d_in[9];
    const float* Wp    = (const float*)d_in[10];
    const float* bp    = (const float*)d_in[11];
    const float* gamma = (const float*)d_in[12];
    const float* beta  = (const float*)d_in[13];
    float* outf = (float*)d_out;

    char* ws = (char*)d_ws;
    unsigned* mask  = (unsigned*)ws;                              // 2 MB
    float*    q     = (float*)(ws + (size_t)(2 << 20));           // 16 MB fp32 [h][n][256]
    ushort_t* kv    = (ushort_t*)(ws + (size_t)(18 << 20));       // 16 MB bf16 [n][2048]
    float*    o     = (float*)(ws + (size_t)(34 << 20));          // 16 MB fp32 [h][n][256]
    float*    concat = q;                                         // alias: q dead after attn
    float*    outp  = (float*)(ws + (size_t)(18 << 20));          // alias: kv dead after attn

    hipMemsetAsync(mask, 0, N_NODES * MWORDS * sizeof(unsigned), stream);
    build_mask_kernel<<<(NEDGE + N_NODES + 255) / 256, 256, 0, stream>>>(ei, mask);

    qkv_kernel<<<dim3(N_NODES / BM, DIM / BN, 12), 256, 0, stream>>>(
        x, Wq, bq, Wk, bk, Wv, bv, q, kv);

    attn_sparse_kernel<<<N_NODES, 256, 0, stream>>>(mask, q, kv, o);

    headout_kernel<<<dim3(N_NODES / BM, DIM / BN, NHEAD), 256, 0, stream>>>(o, Wo, bo, concat);

    finalproj_kernel<<<dim3(N_NODES / BM, DIM / BN), 256, 0, stream>>>(concat, Wp, bp, outp);

    layernorm_kernel<<<N_NODES / 4, 256, 0, stream>>>(outp, gamma, beta, outf);
}

// Round 8
// 269.488 us; speedup vs baseline: 2.4479x; 1.4264x over previous
//
#include <hip/hip_runtime.h>
#include <hip/hip_bf16.h>

#define N_NODES 4096
#define DIM 256
#define NHEAD 4
#define NEDGE 131072
#define MWORDS 128           // 4096 bits / 32 per mask row
#define MAXDEG 192           // mean deg ~65 (Poisson); 192 is >15 sigma
#define KV_STRIDE 2048       // bf16 elems per node: 4 heads x (256 k + 256 v)
#define GBK 64               // GEMM K-step

typedef unsigned short ushort_t;
typedef __attribute__((ext_vector_type(8))) short short8;
typedef __attribute__((ext_vector_type(4))) float f32x4;

__device__ __forceinline__ ushort_t f2bf(float f) {
    unsigned u = __float_as_uint(f);
    unsigned r = u + 0x7FFFu + ((u >> 16) & 1u);   // round-to-nearest-even
    return (ushort_t)(r >> 16);
}
__device__ __forceinline__ float bf2f(ushort_t u) {
    return __uint_as_float((unsigned)u << 16);
}

// ---------------------------------------------------------------- mask build
__global__ __launch_bounds__(256) void build_mask_kernel(const int* __restrict__ ei,
                                                         unsigned* __restrict__ mask) {
    const int t = blockIdx.x * blockDim.x + threadIdx.x;
    if (t < NEDGE) {
        const int r = ei[t] & (N_NODES - 1);
        const int c = ei[NEDGE + t] & (N_NODES - 1);
        atomicOr(&mask[r * MWORDS + (c >> 5)], 1u << (c & 31));
        atomicOr(&mask[c * MWORDS + (r >> 5)], 1u << (r & 31));
    } else if (t < NEDGE + N_NODES) {
        const int i = t - NEDGE;
        atomicOr(&mask[i * MWORDS + (i >> 5)], 1u << (i & 31));
    }
}

// ---------------------------------------------------------------- fused fp32->bf16 converts
// segments (elems): x 1048576 | Wq 262144 | Wk 262144 | Wv 262144 | Wo 262144 | Wp 262144
__global__ __launch_bounds__(256) void convert_all_kernel(
    const float* __restrict__ x,  const float* __restrict__ Wq,
    const float* __restrict__ Wk, const float* __restrict__ Wv,
    const float* __restrict__ Wo, const float* __restrict__ Wp,
    ushort_t* __restrict__ xb, ushort_t* __restrict__ wstack,
    ushort_t* __restrict__ wob, ushort_t* __restrict__ wpb) {
    const int e = (blockIdx.x * blockDim.x + threadIdx.x) << 2;
    const float* src; ushort_t* dst; int off;
    if (e < 1048576)      { src = x;  dst = xb;              off = e; }
    else if (e < 1310720) { src = Wq; dst = wstack;          off = e - 1048576; }
    else if (e < 1572864) { src = Wk; dst = wstack + 262144; off = e - 1310720; }
    else if (e < 1835008) { src = Wv; dst = wstack + 524288; off = e - 1572864; }
    else if (e < 2097152) { src = Wo; dst = wob;             off = e - 1835008; }
    else                  { src = Wp; dst = wpb;             off = e - 2097152; }
    const float4 v = *(const float4*)(src + off);
    ushort4 r;
    r.x = f2bf(v.x); r.y = f2bf(v.y); r.z = f2bf(v.z); r.w = f2bf(v.w);
    *(ushort4*)(dst + off) = r;
}

// ---------------------------------------------------------------- MFMA bf16 GEMM
// D[ch][node] = sum_k Wb[ch][k] * Xb[node][k]  (+bias[ch]); 128x128 tile, 4 waves,
// each wave a 64x64 quadrant of 16x16x32 fragments. A-operand = weight rows (ch),
// B-operand = node rows -> lane's 4 C-regs are 4 consecutive channels (vector store).
// MODE 0: QKV -> qb bf16 [h][node][256] + kvb records. MODE 1: headout -> concat bf16
// [node][1024] (z = head). MODE 2: final -> fp32 [node][256].
template <int MODE>
__global__ __launch_bounds__(256) void mfma_gemm_kernel(
    const ushort_t* __restrict__ Wb, const ushort_t* __restrict__ Xb,
    const float* __restrict__ b0, const float* __restrict__ b1,
    const float* __restrict__ b2,
    ushort_t* __restrict__ qb, ushort_t* __restrict__ kvb,
    void* __restrict__ outp, int K) {
    __shared__ ushort_t Wt[128][GBK + 8];
    __shared__ ushort_t Xt[128][GBK + 8];
    const int tid = threadIdx.x;
    const int lane = tid & 63;
    const int wid = tid >> 6;
    const int wr = wid >> 1, wc = wid & 1;
    const int zoff = (MODE == 1) ? blockIdx.z : 0;
    const ushort_t* Wp_ = Wb + (size_t)zoff * (256 * 256);
    const ushort_t* Xp_ = Xb + (size_t)zoff * ((size_t)N_NODES * 256);
    const int chB = blockIdx.x * 128;
    const int ndB = blockIdx.y * 128;

    f32x4 acc[4][4] = {};

    for (int kt = 0; kt < K; kt += GBK) {
        short8 wreg[4], xreg[4];
#pragma unroll
        for (int i = 0; i < 4; ++i) {
            const int flat = tid + (i << 8);
            const int r = flat >> 3, s = flat & 7;
            wreg[i] = *(const short8*)(Wp_ + (size_t)(chB + r) * K + kt + (s << 3));
            xreg[i] = *(const short8*)(Xp_ + (size_t)(ndB + r) * K + kt + (s << 3));
        }
        __syncthreads();
#pragma unroll
        for (int i = 0; i < 4; ++i) {
            const int flat = tid + (i << 8);
            const int r = flat >> 3, s = flat & 7;
            *(short8*)&Wt[r][s << 3] = wreg[i];
            *(short8*)&Xt[r][s << 3] = xreg[i];
        }
        __syncthreads();
#pragma unroll
        for (int kk = 0; kk < 2; ++kk) {
            short8 af[4], bf[4];
            const int ko = (kk << 5) + ((lane >> 4) << 3);
#pragma unroll
            for (int m = 0; m < 4; ++m)
                af[m] = *(const short8*)&Wt[wr * 64 + m * 16 + (lane & 15)][ko];
#pragma unroll
            for (int n = 0; n < 4; ++n)
                bf[n] = *(const short8*)&Xt[wc * 64 + n * 16 + (lane & 15)][ko];
#pragma unroll
            for (int m = 0; m < 4; ++m)
#pragma unroll
                for (int n = 0; n < 4; ++n)
                    acc[m][n] = __builtin_amdgcn_mfma_f32_16x16x32_bf16(
                        af[m], bf[n], acc[m][n], 0, 0, 0);
        }
    }

    // ---- epilogue
    const int lhi = lane >> 4;       // 0..3
    const int llo = lane & 15;
    int op = 0, h = 0;
    if (MODE == 0) { op = chB >> 10; h = (chB >> 8) & 3; }
#pragma unroll
    for (int m = 0; m < 4; ++m) {
        const int ch = chB + wr * 64 + m * 16 + (lhi << 2);   // +j over 4 regs
        float4 bia;
        if (MODE == 0) {
            const float* bb = (op == 0 ? b0 : op == 1 ? b1 : b2) + (h << 8);
            bia = *(const float4*)&bb[ch & 255];
        } else if (MODE == 1) {
            bia = *(const float4*)&b0[(zoff << 8) + ch];
        } else {
            bia = *(const float4*)&b0[ch];
        }
#pragma unroll
        for (int n = 0; n < 4; ++n) {
            const int node = ndB + wc * 64 + n * 16 + llo;
            const float v0 = acc[m][n][0] + bia.x;
            const float v1 = acc[m][n][1] + bia.y;
            const float v2 = acc[m][n][2] + bia.z;
            const float v3 = acc[m][n][3] + bia.w;
            if (MODE == 2) {
                float4 r; r.x = v0; r.y = v1; r.z = v2; r.w = v3;
                *(float4*)&((float*)outp)[((size_t)node << 8) + ch] = r;
            } else {
                ushort4 r;
                r.x = f2bf(v0); r.y = f2bf(v1); r.z = f2bf(v2); r.w = f2bf(v3);
                if (MODE == 1) {
                    *(ushort4*)&((ushort_t*)outp)[(size_t)node * 1024 + (zoff << 8) + ch] = r;
                } else {
                    const int c = ch & 255;
                    if (op == 0)
                        *(ushort4*)&qb[(((size_t)h * N_NODES + node) << 8) + c] = r;
                    else if (op == 1)
                        *(ushort4*)&kvb[(size_t)node * KV_STRIDE + (h << 9) + c] = r;
                    else
                        *(ushort4*)&kvb[(size_t)node * KV_STRIDE + (h << 9) + 256 + c] = r;
                }
            }
        }
    }
}

// ---------------------------------------------------------------- sparse attention
// one block per node; wave = head. Shared nbr-list decode; serial neighbor loop
// (best L2 hit rate); bf16 q; bf16 k/v fused 1KB record per (node,head); fp32 math.
__global__ __launch_bounds__(256) void attn_sparse_kernel(const unsigned* __restrict__ mask,
                                                          const ushort_t* __restrict__ qb,
                                                          const ushort_t* __restrict__ kv,
                                                          ushort_t* __restrict__ ob) {
    __shared__ int nbr[MAXDEG];
    __shared__ int cnt;
    const int i = blockIdx.x;
    const int tid = threadIdx.x;
    if (tid == 0) cnt = 0;
    __syncthreads();
    if (tid < MWORDS) {
        unsigned m = mask[i * MWORDS + tid];
        while (m) {
            const int b = __ffs(m) - 1;
            m &= m - 1;
            const int pos = atomicAdd(&cnt, 1);
            nbr[pos] = (tid << 5) + b;
        }
    }
    __syncthreads();
    const int deg = cnt;

    const int lane = tid & 63;
    const int h = tid >> 6;

    const ushort4 qu = *(const ushort4*)&qb[(((size_t)h * N_NODES + i) << 8) + (lane << 2)];
    const float qx = bf2f(qu.x), qy = bf2f(qu.y), qz = bf2f(qu.z), qw = bf2f(qu.w);
    const ushort_t* base = kv + (h << 9) + (lane << 2);

    const float SC = 0.0625f * 1.44269504f;   // 1/sqrt(256) * log2(e)
    float denom = 0.f;
    float4 oa = {0.f, 0.f, 0.f, 0.f};

    for (int n = 0; n < deg; ++n) {
        const int j = nbr[n];
        const ushort_t* kp = base + (size_t)j * KV_STRIDE;
        const ushort4 ku = *(const ushort4*)kp;
        const ushort4 vu = *(const ushort4*)(kp + 256);
        float p = qx * bf2f(ku.x) + qy * bf2f(ku.y)
                + qz * bf2f(ku.z) + qw * bf2f(ku.w);
        p += __shfl_xor(p, 1);
        p += __shfl_xor(p, 2);
        p += __shfl_xor(p, 4);
        p += __shfl_xor(p, 8);
        p += __shfl_xor(p, 16);
        p += __shfl_xor(p, 32);
        const float wt = __builtin_amdgcn_exp2f(p * SC);
        denom += wt;
        oa.x += wt * bf2f(vu.x);
        oa.y += wt * bf2f(vu.y);
        oa.z += wt * bf2f(vu.z);
        oa.w += wt * bf2f(vu.w);
    }
    const float inv = 1.0f / denom;
    ushort4 r;
    r.x = f2bf(oa.x * inv); r.y = f2bf(oa.y * inv);
    r.z = f2bf(oa.z * inv); r.w = f2bf(oa.w * inv);
    *(ushort4*)&ob[(((size_t)h * N_NODES + i) << 8) + (lane << 2)] = r;
}

// ---------------------------------------------------------------- layernorm
__global__ __launch_bounds__(256) void layernorm_kernel(const float* __restrict__ inp,
                                                        const float* __restrict__ gamma,
                                                        const float* __restrict__ beta,
                                                        float* __restrict__ out) {
    const int row = (blockIdx.x << 2) + (threadIdx.x >> 6);
    const int lane = threadIdx.x & 63;
    const float4 xv = *(const float4*)&inp[row * DIM + (lane << 2)];
    float s = xv.x + xv.y + xv.z + xv.w;
#pragma unroll
    for (int off = 32; off; off >>= 1) s += __shfl_xor(s, off);
    const float mu = s * (1.0f / DIM);
    const float dx = xv.x - mu, dy = xv.y - mu, dz = xv.z - mu, dw = xv.w - mu;
    float sq = dx * dx + dy * dy + dz * dz + dw * dw;
#pragma unroll
    for (int off = 32; off; off >>= 1) sq += __shfl_xor(sq, off);
    const float inv = 1.0f / sqrtf(sq * (1.0f / DIM) + 1e-5f);
    const float4 gv = *(const float4*)&gamma[lane << 2];
    const float4 bv = *(const float4*)&beta[lane << 2];
    float4 r;
    r.x = dx * inv * gv.x + bv.x;
    r.y = dy * inv * gv.y + bv.y;
    r.z = dz * inv * gv.z + bv.z;
    r.w = dw * inv * gv.w + bv.w;
    *(float4*)&out[row * DIM + (lane << 2)] = r;
}

// ---------------------------------------------------------------- launcher
extern "C" void kernel_launch(void* const* d_in, const int* in_sizes, int n_in,
                              void* d_out, int out_size, void* d_ws, size_t ws_size,
                              hipStream_t stream) {
    const float* x     = (const float*)d_in[0];
    const int*   ei    = (const int*)d_in[1];
    const float* Wq    = (const float*)d_in[2];
    const float* bq    = (const float*)d_in[3];
    const float* Wk    = (const float*)d_in[4];
    const float* bk    = (const float*)d_in[5];
    const float* Wv    = (const float*)d_in[6];
    const float* bv    = (const float*)d_in[7];
    const float* Wo    = (const float*)d_in[8];
    const float* bo    = (const float*)d_in[9];
    const float* Wp    = (const float*)d_in[10];
    const float* bp    = (const float*)d_in[11];
    const float* gamma = (const float*)d_in[12];
    const float* beta  = (const float*)d_in[13];
    float* outf = (float*)d_out;

    char* ws = (char*)d_ws;
    unsigned* mask    = (unsigned*)(ws);                          // 2 MB
    ushort_t* xb      = (ushort_t*)(ws + (size_t)( 2 << 20));     // 2 MB  bf16 [4096][256]
    ushort_t* qb      = (ushort_t*)(ws + (size_t)( 4 << 20));     // 8 MB  bf16 [h][n][256]
    ushort_t* kvb     = (ushort_t*)(ws + (size_t)(12 << 20));     // 16 MB bf16 [n][2048]
    ushort_t* ob      = (ushort_t*)(ws + (size_t)(28 << 20));     // 8 MB  bf16 [h][n][256]
    ushort_t* concatb = (ushort_t*)(ws + (size_t)(36 << 20));     // 8 MB  bf16 [n][1024]
    float*    outp    = (float*)  (ws + (size_t)(44 << 20));      // 4 MB  fp32 [n][256]
    ushort_t* wstack  = (ushort_t*)(ws + (size_t)(48 << 20));     // 1.5 MB bf16 [3072][256]
    ushort_t* wob     = (ushort_t*)(ws + (size_t)(50 << 20));     // 0.5 MB bf16 [1024][256]
    ushort_t* wpb     = (ushort_t*)(ws + (size_t)(51 << 20));     // 0.5 MB bf16 [256][1024]

    hipMemsetAsync(mask, 0, N_NODES * MWORDS * sizeof(unsigned), stream);
    build_mask_kernel<<<(NEDGE + N_NODES + 255) / 256, 256, 0, stream>>>(ei, mask);

    convert_all_kernel<<<2304, 256, 0, stream>>>(x, Wq, Wk, Wv, Wo, Wp,
                                                 xb, wstack, wob, wpb);

    // QKV: R=3072 channels x M=4096 nodes, K=256
    mfma_gemm_kernel<0><<<dim3(24, 32), 256, 0, stream>>>(
        wstack, xb, bq, bk, bv, qb, kvb, nullptr, 256);

    attn_sparse_kernel<<<N_NODES, 256, 0, stream>>>(mask, qb, kvb, ob);

    // headout per head: R=256, M=4096, K=256 -> concat bf16
    mfma_gemm_kernel<1><<<dim3(2, 32, NHEAD), 256, 0, stream>>>(
        wob, ob, bo, nullptr, nullptr, nullptr, nullptr, concatb, 256);

    // final: R=256, M=4096, K=1024 -> fp32
    mfma_gemm_kernel<2><<<dim3(2, 32), 256, 0, stream>>>(
        wpb, concatb, bp, nullptr, nullptr, nullptr, nullptr, outp, 1024);

    layernorm_kernel<<<N_NODES / 4, 256, 0, stream>>>(outp, gamma, beta, outf);
}

// Round 10
// 248.280 us; speedup vs baseline: 2.6570x; 1.0854x over previous
//
#include <hip/hip_runtime.h>
#include <hip/hip_bf16.h>

#define N_NODES 4096
#define DIM 256
#define NHEAD 4
#define NEDGE 131072
#define MWORDS 128           // 4096 bits / 32 per mask row
#define MAXDEG 192           // mean deg ~65 (Poisson); 192 is >15 sigma
#define GBK 64               // GEMM K-step

typedef unsigned short ushort_t;
typedef __attribute__((ext_vector_type(8))) short short8;
typedef __attribute__((ext_vector_type(4))) float f32x4;

__device__ __forceinline__ ushort_t f2bf(float f) {
    unsigned u = __float_as_uint(f);
    unsigned r = u + 0x7FFFu + ((u >> 16) & 1u);   // round-to-nearest-even
    return (ushort_t)(r >> 16);
}
__device__ __forceinline__ float bf2f(ushort_t u) {
    return __uint_as_float((unsigned)u << 16);
}

// ---------------------------------------------------------------- mask build
__global__ __launch_bounds__(256) void build_mask_kernel(const int* __restrict__ ei,
                                                         unsigned* __restrict__ mask) {
    const int t = blockIdx.x * blockDim.x + threadIdx.x;
    if (t < NEDGE) {
        const int r = ei[t] & (N_NODES - 1);
        const int c = ei[NEDGE + t] & (N_NODES - 1);
        atomicOr(&mask[r * MWORDS + (c >> 5)], 1u << (c & 31));
        atomicOr(&mask[c * MWORDS + (r >> 5)], 1u << (r & 31));
    } else if (t < NEDGE + N_NODES) {
        const int i = t - NEDGE;
        atomicOr(&mask[i * MWORDS + (i >> 5)], 1u << (i & 31));
    }
}

// ---------------------------------------------------------------- fused fp32->bf16 converts
// segments (elems): x 1048576 | Wq 262144 | Wk 262144 | Wv 262144 | Wo 262144 | Wp 262144
__global__ __launch_bounds__(256) void convert_all_kernel(
    const float* __restrict__ x,  const float* __restrict__ Wq,
    const float* __restrict__ Wk, const float* __restrict__ Wv,
    const float* __restrict__ Wo, const float* __restrict__ Wp,
    ushort_t* __restrict__ xb, ushort_t* __restrict__ wstack,
    ushort_t* __restrict__ wob, ushort_t* __restrict__ wpb) {
    const int e = (blockIdx.x * blockDim.x + threadIdx.x) << 2;
    const float* src; ushort_t* dst; int off;
    if (e < 1048576)      { src = x;  dst = xb;              off = e; }
    else if (e < 1310720) { src = Wq; dst = wstack;          off = e - 1048576; }
    else if (e < 1572864) { src = Wk; dst = wstack + 262144; off = e - 1310720; }
    else if (e < 1835008) { src = Wv; dst = wstack + 524288; off = e - 1572864; }
    else if (e < 2097152) { src = Wo; dst = wob;             off = e - 1835008; }
    else                  { src = Wp; dst = wpb;             off = e - 2097152; }
    const float4 v = *(const float4*)(src + off);
    ushort4 r;
    r.x = f2bf(v.x); r.y = f2bf(v.y); r.z = f2bf(v.z); r.w = f2bf(v.w);
    *(ushort4*)(dst + off) = r;
}

// ---------------------------------------------------------------- MFMA bf16 GEMM
// D[ch][node] = sum_k Wb[ch][k] * Xb[node][k]  (+bias[ch]); 128x128 tile, 4 waves,
// each wave a 64x64 quadrant of 16x16x32 fragments. A-operand = weight rows (ch),
// B-operand = node rows -> lane's 4 C-regs are 4 consecutive channels (vector store).
// MODE 0: QKV -> qb bf16 [h][node][256] + kvh per-head records [h][node][k256|v256].
// MODE 1: headout -> concat bf16 [node][1024] (z = head). MODE 2: final -> fp32 [node][256].
template <int MODE>
__global__ __launch_bounds__(256) void mfma_gemm_kernel(
    const ushort_t* __restrict__ Wb, const ushort_t* __restrict__ Xb,
    const float* __restrict__ b0, const float* __restrict__ b1,
    const float* __restrict__ b2,
    ushort_t* __restrict__ qb, ushort_t* __restrict__ kvh,
    void* __restrict__ outp, int K) {
    __shared__ ushort_t Wt[128][GBK + 8];
    __shared__ ushort_t Xt[128][GBK + 8];
    const int tid = threadIdx.x;
    const int lane = tid & 63;
    const int wid = tid >> 6;
    const int wr = wid >> 1, wc = wid & 1;
    const int zoff = (MODE == 1) ? blockIdx.z : 0;
    const ushort_t* Wp_ = Wb + (size_t)zoff * (256 * 256);
    const ushort_t* Xp_ = Xb + (size_t)zoff * ((size_t)N_NODES * 256);
    const int chB = blockIdx.x * 128;
    const int ndB = blockIdx.y * 128;

    f32x4 acc[4][4] = {};

    for (int kt = 0; kt < K; kt += GBK) {
        short8 wreg[4], xreg[4];
#pragma unroll
        for (int i = 0; i < 4; ++i) {
            const int flat = tid + (i << 8);
            const int r = flat >> 3, s = flat & 7;
            wreg[i] = *(const short8*)(Wp_ + (size_t)(chB + r) * K + kt + (s << 3));
            xreg[i] = *(const short8*)(Xp_ + (size_t)(ndB + r) * K + kt + (s << 3));
        }
        __syncthreads();
#pragma unroll
        for (int i = 0; i < 4; ++i) {
            const int flat = tid + (i << 8);
            const int r = flat >> 3, s = flat & 7;
            *(short8*)&Wt[r][s << 3] = wreg[i];
            *(short8*)&Xt[r][s << 3] = xreg[i];
        }
        __syncthreads();
#pragma unroll
        for (int kk = 0; kk < 2; ++kk) {
            short8 af[4], bf[4];
            const int ko = (kk << 5) + ((lane >> 4) << 3);
#pragma unroll
            for (int m = 0; m < 4; ++m)
                af[m] = *(const short8*)&Wt[wr * 64 + m * 16 + (lane & 15)][ko];
#pragma unroll
            for (int n = 0; n < 4; ++n)
                bf[n] = *(const short8*)&Xt[wc * 64 + n * 16 + (lane & 15)][ko];
#pragma unroll
            for (int m = 0; m < 4; ++m)
#pragma unroll
                for (int n = 0; n < 4; ++n)
                    acc[m][n] = __builtin_amdgcn_mfma_f32_16x16x32_bf16(
                        af[m], bf[n], acc[m][n], 0, 0, 0);
        }
    }

    // ---- epilogue
    const int lhi = lane >> 4;       // 0..3
    const int llo = lane & 15;
    int op = 0, h = 0;
    if (MODE == 0) { op = chB >> 10; h = (chB >> 8) & 3; }
#pragma unroll
    for (int m = 0; m < 4; ++m) {
        const int ch = chB + wr * 64 + m * 16 + (lhi << 2);   // +j over 4 regs
        float4 bia;
        if (MODE == 0) {
            const float* bb = (op == 0 ? b0 : op == 1 ? b1 : b2) + (h << 8);
            bia = *(const float4*)&bb[ch & 255];
        } else if (MODE == 1) {
            bia = *(const float4*)&b0[(zoff << 8) + ch];
        } else {
            bia = *(const float4*)&b0[ch];
        }
#pragma unroll
        for (int n = 0; n < 4; ++n) {
            const int node = ndB + wc * 64 + n * 16 + llo;
            const float v0 = acc[m][n][0] + bia.x;
            const float v1 = acc[m][n][1] + bia.y;
            const float v2 = acc[m][n][2] + bia.z;
            const float v3 = acc[m][n][3] + bia.w;
            if (MODE == 2) {
                float4 r; r.x = v0; r.y = v1; r.z = v2; r.w = v3;
                *(float4*)&((float*)outp)[((size_t)node << 8) + ch] = r;
            } else {
                ushort4 r;
                r.x = f2bf(v0); r.y = f2bf(v1); r.z = f2bf(v2); r.w = f2bf(v3);
                if (MODE == 1) {
                    *(ushort4*)&((ushort_t*)outp)[(size_t)node * 1024 + (zoff << 8) + ch] = r;
                } else {
                    const int c = ch & 255;
                    if (op == 0)
                        *(ushort4*)&qb[(((size_t)h * N_NODES + node) << 8) + c] = r;
                    else if (op == 1)
                        *(ushort4*)&kvh[(((size_t)h * N_NODES + node) << 9) + c] = r;
                    else
                        *(ushort4*)&kvh[(((size_t)h * N_NODES + node) << 9) + 256 + c] = r;
                }
            }
        }
    }
}

// ---------------------------------------------------------------- sparse attention
// XCD-pinned per-head partition: xcd = bid & 7 (empirical round-robin dispatch),
// head = xcd >> 1 -> XCD pair {2h,2h+1} touches ONLY head h's 4MB kv slice, which
// fits that XCD's 4MB L2. Block = 4 waves = 4 nodes of that head; each wave decodes
// its own mask row (lane-parallel) then runs the serial bf16 gather.
__global__ __launch_bounds__(256) void attn_sparse_kernel(const unsigned* __restrict__ mask,
                                                          const ushort_t* __restrict__ qb,
                                                          const ushort_t* __restrict__ kvh,
                                                          ushort_t* __restrict__ ob) {
    __shared__ int nbr[4][MAXDEG];
    __shared__ int cnt[4];
    const int tid = threadIdx.x;
    const int w = tid >> 6;
    const int lane = tid & 63;
    const int xcd = blockIdx.x & 7;
    const int h = xcd >> 1;
    const int node = ((xcd & 1) << 11) + ((blockIdx.x >> 3) << 2) + w;

    if (lane == 0) cnt[w] = 0;
    __syncthreads();
    // decode own row: each lane scans 2 mask words
    for (int t = lane; t < MWORDS; t += 64) {
        unsigned m = mask[node * MWORDS + t];
        while (m) {
            const int b = __ffs(m) - 1;
            m &= m - 1;
            const int pos = atomicAdd(&cnt[w], 1);
            if (pos < MAXDEG) nbr[w][pos] = (t << 5) + b;
        }
    }
    __syncthreads();
    const int deg = cnt[w] < MAXDEG ? cnt[w] : MAXDEG;

    const ushort4 qu = *(const ushort4*)&qb[(((size_t)h * N_NODES + node) << 8) + (lane << 2)];
    const float qx = bf2f(qu.x), qy = bf2f(qu.y), qz = bf2f(qu.z), qw = bf2f(qu.w);
    const ushort_t* base = kvh + ((size_t)h * N_NODES << 9) + (lane << 2);

    const float SC = 0.0625f * 1.44269504f;   // 1/sqrt(256) * log2(e)
    float denom = 0.f;
    float4 oa = {0.f, 0.f, 0.f, 0.f};

    for (int n = 0; n < deg; ++n) {
        const int j = nbr[w][n];
        const ushort_t* kp = base + ((size_t)j << 9);
        const ushort4 ku = *(const ushort4*)kp;
        const ushort4 vu = *(const ushort4*)(kp + 256);
        float p = qx * bf2f(ku.x) + qy * bf2f(ku.y)
                + qz * bf2f(ku.z) + qw * bf2f(ku.w);
        p += __shfl_xor(p, 1);
        p += __shfl_xor(p, 2);
        p += __shfl_xor(p, 4);
        p += __shfl_xor(p, 8);
        p += __shfl_xor(p, 16);
        p += __shfl_xor(p, 32);
        const float wt = __builtin_amdgcn_exp2f(p * SC);
        denom += wt;
        oa.x += wt * bf2f(vu.x);
        oa.y += wt * bf2f(vu.y);
        oa.z += wt * bf2f(vu.z);
        oa.w += wt * bf2f(vu.w);
    }
    const float inv = 1.0f / denom;
    ushort4 r;
    r.x = f2bf(oa.x * inv); r.y = f2bf(oa.y * inv);
    r.z = f2bf(oa.z * inv); r.w = f2bf(oa.w * inv);
    *(ushort4*)&ob[(((size_t)h * N_NODES + node) << 8) + (lane << 2)] = r;
}

// ---------------------------------------------------------------- layernorm
__global__ __launch_bounds__(256) void layernorm_kernel(const float* __restrict__ inp,
                                                        const float* __restrict__ gamma,
                                                        const float* __restrict__ beta,
                                                        float* __restrict__ out) {
    const int row = (blockIdx.x << 2) + (threadIdx.x >> 6);
    const int lane = threadIdx.x & 63;
    const float4 xv = *(const float4*)&inp[row * DIM + (lane << 2)];
    float s = xv.x + xv.y + xv.z + xv.w;
#pragma unroll
    for (int off = 32; off; off >>= 1) s += __shfl_xor(s, off);
    const float mu = s * (1.0f / DIM);
    const float dx = xv.x - mu, dy = xv.y - mu, dz = xv.z - mu, dw = xv.w - mu;
    float sq = dx * dx + dy * dy + dz * dz + dw * dw;
#pragma unroll
    for (int off = 32; off; off >>= 1) sq += __shfl_xor(sq, off);
    const float inv = 1.0f / sqrtf(sq * (1.0f / DIM) + 1e-5f);
    const float4 gv = *(const float4*)&gamma[lane << 2];
    const float4 bv = *(const float4*)&beta[lane << 2];
    float4 r;
    r.x = dx * inv * gv.x + bv.x;
    r.y = dy * inv * gv.y + bv.y;
    r.z = dz * inv * gv.z + bv.z;
    r.w = dw * inv * gv.w + bv.w;
    *(float4*)&out[row * DIM + (lane << 2)] = r;
}

// ---------------------------------------------------------------- launcher
extern "C" void kernel_launch(void* const* d_in, const int* in_sizes, int n_in,
                              void* d_out, int out_size, void* d_ws, size_t ws_size,
                              hipStream_t stream) {
    const float* x     = (const float*)d_in[0];
    const int*   ei    = (const int*)d_in[1];
    const float* Wq    = (const float*)d_in[2];
    const float* bq    = (const float*)d_in[3];
    const float* Wk    = (const float*)d_in[4];
    const float* bk    = (const float*)d_in[5];
    const float* Wv    = (const float*)d_in[6];
    const float* bv    = (const float*)d_in[7];
    const float* Wo    = (const float*)d_in[8];
    const float* bo    = (const float*)d_in[9];
    const float* Wp    = (const float*)d_in[10];
    const float* bp    = (const float*)d_in[11];
    const float* gamma = (const float*)d_in[12];
    const float* beta  = (const float*)d_in[13];
    float* outf = (float*)d_out;

    char* ws = (char*)d_ws;
    unsigned* mask    = (unsigned*)(ws);                          // 2 MB
    ushort_t* xb      = (ushort_t*)(ws + (size_t)( 2 << 20));     // 2 MB  bf16 [4096][256]
    ushort_t* qb      = (ushort_t*)(ws + (size_t)( 4 << 20));     // 8 MB  bf16 [h][n][256]
    ushort_t* kvh     = (ushort_t*)(ws + (size_t)(12 << 20));     // 16 MB bf16 [h][n][512]
    ushort_t* ob      = (ushort_t*)(ws + (size_t)(28 << 20));     // 8 MB  bf16 [h][n][256]
    ushort_t* concatb = (ushort_t*)(ws + (size_t)(36 << 20));     // 8 MB  bf16 [n][1024]
    float*    outp    = (float*)  (ws + (size_t)(44 << 20));      // 4 MB  fp32 [n][256]
    ushort_t* wstack  = (ushort_t*)(ws + (size_t)(48 << 20));     // 1.5 MB bf16 [3072][256]
    ushort_t* wob     = (ushort_t*)(ws + (size_t)(50 << 20));     // 0.5 MB bf16 [1024][256]
    ushort_t* wpb     = (ushort_t*)(ws + (size_t)(51 << 20));     // 0.5 MB bf16 [256][1024]

    hipMemsetAsync(mask, 0, N_NODES * MWORDS * sizeof(unsigned), stream);
    build_mask_kernel<<<(NEDGE + N_NODES + 255) / 256, 256, 0, stream>>>(ei, mask);

    convert_all_kernel<<<2304, 256, 0, stream>>>(x, Wq, Wk, Wv, Wo, Wp,
                                                 xb, wstack, wob, wpb);

    // QKV: R=3072 channels x M=4096 nodes, K=256
    mfma_gemm_kernel<0><<<dim3(24, 32), 256, 0, stream>>>(
        wstack, xb, bq, bk, bv, qb, kvh, nullptr, 256);

    attn_sparse_kernel<<<N_NODES, 256, 0, stream>>>(mask, qb, kvh, ob);

    // headout per head: R=256, M=4096, K=256 -> concat bf16
    mfma_gemm_kernel<1><<<dim3(2, 32, NHEAD), 256, 0, stream>>>(
        wob, ob, bo, nullptr, nullptr, nullptr, nullptr, concatb, 256);

    // final: R=256, M=4096, K=1024 -> fp32
    mfma_gemm_kernel<2><<<dim3(2, 32), 256, 0, stream>>>(
        wpb, concatb, bp, nullptr, nullptr, nullptr, nullptr, outp, 1024);

    layernorm_kernel<<<N_NODES / 4, 256, 0, stream>>>(outp, gamma, beta, outf);
}

// Round 13
// 201.730 us; speedup vs baseline: 3.2701x; 1.2308x over previous
//
#include <hip/hip_runtime.h>
#include <hip/hip_bf16.h>

#define N_NODES 4096
#define DIM 256
#define NHEAD 4
#define NEDGE 131072
#define MWORDS 128           // 4096 bits / 32 per mask row
#define MAXDEG 192           // mean deg ~65 (Poisson); 192 is >15 sigma
#define GBK 64               // GEMM K-step

typedef unsigned short ushort_t;
typedef __attribute__((ext_vector_type(8))) short short8;
typedef __attribute__((ext_vector_type(4))) float f32x4;

__device__ __forceinline__ ushort_t f2bf(float f) {
    unsigned u = __float_as_uint(f);
    unsigned r = u + 0x7FFFu + ((u >> 16) & 1u);   // round-to-nearest-even
    return (ushort_t)(r >> 16);
}
__device__ __forceinline__ float bf2f(ushort_t u) {
    return __uint_as_float((unsigned)u << 16);
}

// ---------------------------------------------------------------- mask build
__global__ __launch_bounds__(256) void build_mask_kernel(const int* __restrict__ ei,
                                                         unsigned* __restrict__ mask) {
    const int t = blockIdx.x * blockDim.x + threadIdx.x;
    if (t < NEDGE) {
        const int r = ei[t] & (N_NODES - 1);
        const int c = ei[NEDGE + t] & (N_NODES - 1);
        atomicOr(&mask[r * MWORDS + (c >> 5)], 1u << (c & 31));
        atomicOr(&mask[c * MWORDS + (r >> 5)], 1u << (r & 31));
    } else if (t < NEDGE + N_NODES) {
        const int i = t - NEDGE;
        atomicOr(&mask[i * MWORDS + (i >> 5)], 1u << (i & 31));
    }
}

// ---------------------------------------------------------------- fused fp32->bf16 converts
// segments (elems): x 1048576 | Wq 262144 | Wk 262144 | Wv 262144 | Wo 262144 | Wp 262144
__global__ __launch_bounds__(256) void convert_all_kernel(
    const float* __restrict__ x,  const float* __restrict__ Wq,
    const float* __restrict__ Wk, const float* __restrict__ Wv,
    const float* __restrict__ Wo, const float* __restrict__ Wp,
    ushort_t* __restrict__ xb, ushort_t* __restrict__ wstack,
    ushort_t* __restrict__ wob, ushort_t* __restrict__ wpb) {
    const int e = (blockIdx.x * blockDim.x + threadIdx.x) << 2;
    const float* src; ushort_t* dst; int off;
    if (e < 1048576)      { src = x;  dst = xb;              off = e; }
    else if (e < 1310720) { src = Wq; dst = wstack;          off = e - 1048576; }
    else if (e < 1572864) { src = Wk; dst = wstack + 262144; off = e - 1310720; }
    else if (e < 1835008) { src = Wv; dst = wstack + 524288; off = e - 1572864; }
    else if (e < 2097152) { src = Wo; dst = wob;             off = e - 1835008; }
    else                  { src = Wp; dst = wpb;             off = e - 2097152; }
    const float4 v = *(const float4*)(src + off);
    ushort4 r;
    r.x = f2bf(v.x); r.y = f2bf(v.y); r.z = f2bf(v.z); r.w = f2bf(v.w);
    *(ushort4*)(dst + off) = r;
}

// ---------------------------------------------------------------- MFMA bf16 GEMM
// D[ch][node] = sum_k Wb[ch][k] * Xb[node][k]  (+bias[ch]); 128x128 tile, 4 waves,
// each wave a 64x64 quadrant of 16x16x32 fragments. A-operand = weight rows (ch),
// B-operand = node rows -> lane's 4 C-regs are 4 consecutive channels (vector store).
// MODE 0: QKV -> qb bf16 [h][node][256] + kvh per-head records [h][node][k256|v256].
// MODE 1: headout -> concat bf16 [node][1024] (z = head). MODE 2: final -> fp32 [node][256].
template <int MODE>
__global__ __launch_bounds__(256) void mfma_gemm_kernel(
    const ushort_t* __restrict__ Wb, const ushort_t* __restrict__ Xb,
    const float* __restrict__ b0, const float* __restrict__ b1,
    const float* __restrict__ b2,
    ushort_t* __restrict__ qb, ushort_t* __restrict__ kvh,
    void* __restrict__ outp, int K) {
    __shared__ ushort_t Wt[128][GBK + 8];
    __shared__ ushort_t Xt[128][GBK + 8];
    const int tid = threadIdx.x;
    const int lane = tid & 63;
    const int wid = tid >> 6;
    const int wr = wid >> 1, wc = wid & 1;
    const int zoff = (MODE == 1) ? blockIdx.z : 0;
    const ushort_t* Wp_ = Wb + (size_t)zoff * (256 * 256);
    const ushort_t* Xp_ = Xb + (size_t)zoff * ((size_t)N_NODES * 256);
    const int chB = blockIdx.x * 128;
    const int ndB = blockIdx.y * 128;

    f32x4 acc[4][4] = {};

    for (int kt = 0; kt < K; kt += GBK) {
        short8 wreg[4], xreg[4];
#pragma unroll
        for (int i = 0; i < 4; ++i) {
            const int flat = tid + (i << 8);
            const int r = flat >> 3, s = flat & 7;
            wreg[i] = *(const short8*)(Wp_ + (size_t)(chB + r) * K + kt + (s << 3));
            xreg[i] = *(const short8*)(Xp_ + (size_t)(ndB + r) * K + kt + (s << 3));
        }
        __syncthreads();
#pragma unroll
        for (int i = 0; i < 4; ++i) {
            const int flat = tid + (i << 8);
            const int r = flat >> 3, s = flat & 7;
            *(short8*)&Wt[r][s << 3] = wreg[i];
            *(short8*)&Xt[r][s << 3] = xreg[i];
        }
        __syncthreads();
#pragma unroll
        for (int kk = 0; kk < 2; ++kk) {
            short8 af[4], bf[4];
            const int ko = (kk << 5) + ((lane >> 4) << 3);
#pragma unroll
            for (int m = 0; m < 4; ++m)
                af[m] = *(const short8*)&Wt[wr * 64 + m * 16 + (lane & 15)][ko];
#pragma unroll
            for (int n = 0; n < 4; ++n)
                bf[n] = *(const short8*)&Xt[wc * 64 + n * 16 + (lane & 15)][ko];
#pragma unroll
            for (int m = 0; m < 4; ++m)
#pragma unroll
                for (int n = 0; n < 4; ++n)
                    acc[m][n] = __builtin_amdgcn_mfma_f32_16x16x32_bf16(
                        af[m], bf[n], acc[m][n], 0, 0, 0);
        }
    }

    // ---- epilogue
    const int lhi = lane >> 4;       // 0..3
    const int llo = lane & 15;
    int op = 0, h = 0;
    if (MODE == 0) { op = chB >> 10; h = (chB >> 8) & 3; }
#pragma unroll
    for (int m = 0; m < 4; ++m) {
        const int ch = chB + wr * 64 + m * 16 + (lhi << 2);   // +j over 4 regs
        float4 bia;
        if (MODE == 0) {
            const float* bb = (op == 0 ? b0 : op == 1 ? b1 : b2) + (h << 8);
            bia = *(const float4*)&bb[ch & 255];
        } else if (MODE == 1) {
            bia = *(const float4*)&b0[(zoff << 8) + ch];
        } else {
            bia = *(const float4*)&b0[ch];
        }
#pragma unroll
        for (int n = 0; n < 4; ++n) {
            const int node = ndB + wc * 64 + n * 16 + llo;
            const float v0 = acc[m][n][0] + bia.x;
            const float v1 = acc[m][n][1] + bia.y;
            const float v2 = acc[m][n][2] + bia.z;
            const float v3 = acc[m][n][3] + bia.w;
            if (MODE == 2) {
                float4 r; r.x = v0; r.y = v1; r.z = v2; r.w = v3;
                *(float4*)&((float*)outp)[((size_t)node << 8) + ch] = r;
            } else {
                ushort4 r;
                r.x = f2bf(v0); r.y = f2bf(v1); r.z = f2bf(v2); r.w = f2bf(v3);
                if (MODE == 1) {
                    *(ushort4*)&((ushort_t*)outp)[(size_t)node * 1024 + (zoff << 8) + ch] = r;
                } else {
                    const int c = ch & 255;
                    if (op == 0)
                        *(ushort4*)&qb[(((size_t)h * N_NODES + node) << 8) + c] = r;
                    else if (op == 1)
                        *(ushort4*)&kvh[(((size_t)h * N_NODES + node) << 9) + c] = r;
                    else
                        *(ushort4*)&kvh[(((size_t)h * N_NODES + node) << 9) + 256 + c] = r;
                }
            }
        }
    }
}

// ---------------------------------------------------------------- sparse attention
// XCD-pinned per-head partition (round-10 proven: FETCH 364->37MB). New this round:
// (a) atomic-free decode via popcount + shfl_up prefix scan (kills 901K LDS
//     bank-conflict cycles + serialization), (b) 4-neighbor subgroup gather
//     (16-lane sub-dots) for 4x chain amortization -- safe now that the per-head
//     4MB kv slice is L2-resident on its pinned XCD.
__global__ __launch_bounds__(256) void attn_sparse_kernel(const unsigned* __restrict__ mask,
                                                          const ushort_t* __restrict__ qb,
                                                          const ushort_t* __restrict__ kvh,
                                                          ushort_t* __restrict__ ob) {
    __shared__ int nbr[4][MAXDEG];
    const int tid = threadIdx.x;
    const int w = tid >> 6;
    const int lane = tid & 63;
    const int xcd = blockIdx.x & 7;
    const int h = xcd >> 1;
    const int node = ((xcd & 1) << 11) + ((blockIdx.x >> 3) << 2) + w;

    // ---- decode own row, atomic-free: lane scans words lane and lane+64
    const unsigned m0 = mask[node * MWORDS + lane];
    const unsigned m1 = mask[node * MWORDS + 64 + lane];
    const int c = __popc(m0) + __popc(m1);
    int s = c;
#pragma unroll
    for (int d = 1; d < 64; d <<= 1) {
        const int t = __shfl_up(s, d);
        if (lane >= d) s += t;
    }
    const int deg0 = __shfl(s, 63);
    const int deg = deg0 < MAXDEG ? deg0 : MAXDEG;
    int pos = s - c;                 // exclusive prefix = this lane's write base
    unsigned mm = m0;
    int bj = lane << 5;
    while (mm) {
        const int b = __ffs(mm) - 1; mm &= mm - 1;
        if (pos < MAXDEG) nbr[w][pos] = bj + b;
        ++pos;
    }
    mm = m1; bj = (lane + 64) << 5;
    while (mm) {
        const int b = __ffs(mm) - 1; mm &= mm - 1;
        if (pos < MAXDEG) nbr[w][pos] = bj + b;
        ++pos;
    }
    __syncthreads();   // cheap (once); guarantees LDS visibility

    // ---- gather: 4 neighbors concurrently (sub = lane>>4), 16-lane sub-dots
    const int sub = lane >> 4;
    const int sl = lane & 15;        // lane's 16-dim slice

    const ushort_t* qp = qb + (((size_t)h * N_NODES + node) << 8) + (sl << 4);
    const short8 q0 = *(const short8*)qp;
    const short8 q1 = *(const short8*)(qp + 8);
    float qf[16];
#pragma unroll
    for (int i = 0; i < 8; ++i) {
        qf[i] = bf2f((ushort_t)q0[i]);
        qf[8 + i] = bf2f((ushort_t)q1[i]);
    }
    float oa[16];
#pragma unroll
    for (int i = 0; i < 16; ++i) oa[i] = 0.f;
    float denom = 0.f;

    const ushort_t* kbase = kvh + (((size_t)h * N_NODES) << 9) + (sl << 4);
    const float SC = 0.0625f * 1.44269504f;   // 1/sqrt(256) * log2(e)

    for (int n0 = 0; n0 < deg; n0 += 4) {
        const int idx = n0 + sub;
        const bool valid = idx < deg;
        const int j = nbr[w][valid ? idx : 0];
        const ushort_t* kp = kbase + ((size_t)j << 9);
        const short8 k0 = *(const short8*)kp;
        const short8 k1 = *(const short8*)(kp + 8);
        const short8 v0 = *(const short8*)(kp + 256);
        const short8 v1 = *(const short8*)(kp + 264);
        float p = 0.f;
#pragma unroll
        for (int i = 0; i < 8; ++i)
            p += qf[i] * bf2f((ushort_t)k0[i]) + qf[8 + i] * bf2f((ushort_t)k1[i]);
        p += __shfl_xor(p, 1);
        p += __shfl_xor(p, 2);
        p += __shfl_xor(p, 4);
        p += __shfl_xor(p, 8);
        const float wt = valid ? __builtin_amdgcn_exp2f(p * SC) : 0.f;
        denom += wt;
#pragma unroll
        for (int i = 0; i < 8; ++i) {
            oa[i] += wt * bf2f((ushort_t)v0[i]);
            oa[8 + i] += wt * bf2f((ushort_t)v1[i]);
        }
    }
    denom += __shfl_xor(denom, 16);
    denom += __shfl_xor(denom, 32);
#pragma unroll
    for (int i = 0; i < 16; ++i) {
        oa[i] += __shfl_xor(oa[i], 16);
        oa[i] += __shfl_xor(oa[i], 32);
    }
    if (sub == 0) {
        const float inv = 1.0f / denom;
        short8 r0, r1;
#pragma unroll
        for (int i = 0; i < 8; ++i) {
            r0[i] = (short)f2bf(oa[i] * inv);
            r1[i] = (short)f2bf(oa[8 + i] * inv);
        }
        ushort_t* op_ = ob + (((size_t)h * N_NODES + node) << 8) + (sl << 4);
        *(short8*)op_ = r0;
        *(short8*)(op_ + 8) = r1;
    }
}

// ---------------------------------------------------------------- layernorm
__global__ __launch_bounds__(256) void layernorm_kernel(const float* __restrict__ inp,
                                                        const float* __restrict__ gamma,
                                                        const float* __restrict__ beta,
                                                        float* __restrict__ out) {
    const int row = (blockIdx.x << 2) + (threadIdx.x >> 6);
    const int lane = threadIdx.x & 63;
    const float4 xv = *(const float4*)&inp[row * DIM + (lane << 2)];
    float s = xv.x + xv.y + xv.z + xv.w;
#pragma unroll
    for (int off = 32; off; off >>= 1) s += __shfl_xor(s, off);
    const float mu = s * (1.0f / DIM);
    const float dx = xv.x - mu, dy = xv.y - mu, dz = xv.z - mu, dw = xv.w - mu;
    float sq = dx * dx + dy * dy + dz * dz + dw * dw;
#pragma unroll
    for (int off = 32; off; off >>= 1) sq += __shfl_xor(sq, off);
    const float inv = 1.0f / sqrtf(sq * (1.0f / DIM) + 1e-5f);
    const float4 gv = *(const float4*)&gamma[lane << 2];
    const float4 bv = *(const float4*)&beta[lane << 2];
    float4 r;
    r.x = dx * inv * gv.x + bv.x;
    r.y = dy * inv * gv.y + bv.y;
    r.z = dz * inv * gv.z + bv.z;
    r.w = dw * inv * gv.w + bv.w;
    *(float4*)&out[row * DIM + (lane << 2)] = r;
}

// ---------------------------------------------------------------- launcher
extern "C" void kernel_launch(void* const* d_in, const int* in_sizes, int n_in,
                              void* d_out, int out_size, void* d_ws, size_t ws_size,
                              hipStream_t stream) {
    const float* x     = (const float*)d_in[0];
    const int*   ei    = (const int*)d_in[1];
    const float* Wq    = (const float*)d_in[2];
    const float* bq    = (const float*)d_in[3];
    const float* Wk    = (const float*)d_in[4];
    const float* bk    = (const float*)d_in[5];
    const float* Wv    = (const float*)d_in[6];
    const float* bv    = (const float*)d_in[7];
    const float* Wo    = (const float*)d_in[8];
    const float* bo    = (const float*)d_in[9];
    const float* Wp    = (const float*)d_in[10];
    const float* bp    = (const float*)d_in[11];
    const float* gamma = (const float*)d_in[12];
    const float* beta  = (const float*)d_in[13];
    float* outf = (float*)d_out;

    char* ws = (char*)d_ws;
    unsigned* mask    = (unsigned*)(ws);                          // 2 MB
    ushort_t* xb      = (ushort_t*)(ws + (size_t)( 2 << 20));     // 2 MB  bf16 [4096][256]
    ushort_t* qb      = (ushort_t*)(ws + (size_t)( 4 << 20));     // 8 MB  bf16 [h][n][256]
    ushort_t* kvh     = (ushort_t*)(ws + (size_t)(12 << 20));     // 16 MB bf16 [h][n][512]
    ushort_t* ob      = (ushort_t*)(ws + (size_t)(28 << 20));     // 8 MB  bf16 [h][n][256]
    ushort_t* concatb = (ushort_t*)(ws + (size_t)(36 << 20));     // 8 MB  bf16 [n][1024]
    float*    outp    = (float*)  (ws + (size_t)(44 << 20));      // 4 MB  fp32 [n][256]
    ushort_t* wstack  = (ushort_t*)(ws + (size_t)(48 << 20));     // 1.5 MB bf16 [3072][256]
    ushort_t* wob     = (ushort_t*)(ws + (size_t)(50 << 20));     // 0.5 MB bf16 [1024][256]
    ushort_t* wpb     = (ushort_t*)(ws + (size_t)(51 << 20));     // 0.5 MB bf16 [256][1024]

    hipMemsetAsync(mask, 0, N_NODES * MWORDS * sizeof(unsigned), stream);
    build_mask_kernel<<<(NEDGE + N_NODES + 255) / 256, 256, 0, stream>>>(ei, mask);

    convert_all_kernel<<<2304, 256, 0, stream>>>(x, Wq, Wk, Wv, Wo, Wp,
                                                 xb, wstack, wob, wpb);

    // QKV: R=3072 channels x M=4096 nodes, K=256
    mfma_gemm_kernel<0><<<dim3(24, 32), 256, 0, stream>>>(
        wstack, xb, bq, bk, bv, qb, kvh, nullptr, 256);

    attn_sparse_kernel<<<N_NODES, 256, 0, stream>>>(mask, qb, kvh, ob);

    // headout per head: R=256, M=4096, K=256 -> concat bf16
    mfma_gemm_kernel<1><<<dim3(2, 32, NHEAD), 256, 0, stream>>>(
        wob, ob, bo, nullptr, nullptr, nullptr, nullptr, concatb, 256);

    // final: R=256, M=4096, K=1024 -> fp32
    mfma_gemm_kernel<2><<<dim3(2, 32), 256, 0, stream>>>(
        wpb, concatb, bp, nullptr, nullptr, nullptr, nullptr, outp, 1024);

    layernorm_kernel<<<N_NODES / 4, 256, 0, stream>>>(outp, gamma, beta, outf);
}